// Round 19
// baseline (216.780 us; speedup 1.0000x reference)
//
#include <hip/hip_runtime.h>
#include <hip/hip_bf16.h>
#include <math.h>

#define KD 1024
#define VD 50000
#define BD 2048
#define WDIM 20
#define THRV 1e-10f
#define PI_F 3.14159274101257324f  /* 0x40490FDB — f32(pi) */

#define CHUNK 10000     /* complex elems per chunk = 80 KB; 5*10000 = VD, no tail */
#define NCHUNK 5

// d_out is FLOAT32[2049]: [0..2048) = mu (as float), [2048] = E.
//
// Round-19: r18 (182.7us) + TLP overlap. 100KB LDS forced 1 block/CU ->
// stream(HBM) and match/score(VALU) serialized. Now: 80KB chunks, 512 thr
// (512,4) -> 2 blocks/CU co-resident at offset phases (one streams while the
// other computes). Grid = row x half (2x stream, L2-absorbed via XCD pairing,
// validated r10/r11). Spill checklist: no asm, no gload_lds, no pf-regs,
// 512thr budget 128 (r17: 108 clean). Score math bit-identical to r5-r18.

// ---------------------------------------------------------------------------
// prep: cst[w][b]=(cos,sin)(pi*pos[b][w]); idp[j][b] = packed u16 id pairs.
// ---------------------------------------------------------------------------
__global__ __launch_bounds__(256) void prep_kernel(
    const float* __restrict__ pos,
    const int*   __restrict__ ids,
    float2* __restrict__ cst,
    unsigned int* __restrict__ idp)
{
    const int b = blockIdx.x * 256 + threadIdx.x;
    if (b >= BD) return;
    int idv[WDIM];
#pragma unroll
    for (int w = 0; w < WDIM; ++w) {
        idv[w] = ids[b * WDIM + w];
        const float pf = __fmul_rn(pos[b * WDIM + w], PI_F);
        cst[w * BD + b] = make_float2(cosf(pf), sinf(pf));
    }
#pragma unroll
    for (int j = 0; j < WDIM / 2; ++j)
        idp[j * BD + b] = (unsigned int)idv[2 * j] |
                          ((unsigned int)idv[2 * j + 1] << 16);
}

// ---------------------------------------------------------------------------
// zero the 2048 u64 argmax accumulators (every call — ws poisoned 0xAA)
// ---------------------------------------------------------------------------
__global__ __launch_bounds__(256) void zero64_kernel(unsigned long long* amax) {
    const int i = blockIdx.x * 256 + threadIdx.x;
    if (i < BD) amax[i] = 0ull;
}

// ---------------------------------------------------------------------------
// half_kernel: grid 2048 = (row k) x (half). 512 thr, 2 b/thread.
// Per chunk: sync, stream 80KB -> LDS (+norm), sync, predicated copy-match.
// Tail: norm reduce (half 0 writes), score math, packed-u64 atomicMax.
// ---------------------------------------------------------------------------
__global__ __launch_bounds__(512, 4) void half_kernel(
    const float* __restrict__ W,
    const unsigned int* __restrict__ idp,
    const float2* __restrict__ cst,
    float* __restrict__ norm2,
    unsigned long long* __restrict__ amax)
{
    __shared__ __align__(16) float chunk[CHUNK * 2];   // 80 KB
    __shared__ float sm[8];

    const int t = threadIdx.x;
    // XCD pair swizzle: both halves of row k adjacent on one XCD
    const int g    = blockIdx.x;
    const int slot = g >> 3;
    const int k    = (g & 7) + 8 * (slot >> 1);
    const int half = slot & 1;
    const int b0   = half * 1024 + t;
    const int b1   = b0 + 512;

    const float* Wk = W + (size_t)k * (VD * 2);

    unsigned int idreg[2][WDIM / 2];
#pragma unroll
    for (int j = 0; j < WDIM / 2; ++j) {
        idreg[0][j] = idp[j * BD + b0];
        idreg[1][j] = idp[j * BD + b1];
    }

    float gx[2][WDIM], gy[2][WDIM];
#pragma unroll
    for (int w = 0; w < WDIM; ++w) {
        gx[0][w] = 0.f; gy[0][w] = 0.f; gx[1][w] = 0.f; gy[1][w] = 0.f;
    }

    float nacc = 0.0f;

    for (int c = 0; c < NCHUNK; ++c) {
        __syncthreads();   // previous chunk's readers done
        // ---- coalesced chunk stream + norm2 partial ----
        const float4* src = reinterpret_cast<const float4*>(Wk + (size_t)c * (CHUNK * 2));
        float4* dst = reinterpret_cast<float4*>(chunk);
        for (int i = t; i < (CHUNK * 2) / 4; i += 512) {
            const float4 v = src[i];
            dst[i] = v;
            nacc += v.x * v.x + v.y * v.y + v.z * v.z + v.w * v.w;
        }
        __syncthreads();   // chunk visible

        // ---- match phase: predicated copy for ids inside this chunk ----
        const int lo = c * CHUNK;
#pragma unroll
        for (int bb = 0; bb < 2; ++bb) {
#pragma unroll
            for (int w = 0; w < WDIM; ++w) {
                const int id  = (int)((idreg[bb][w >> 1] >> ((w & 1) * 16)) & 0xFFFFu);
                const int off = id - lo;
                const bool m  = (unsigned)off < (unsigned)CHUNK;
                const int a   = m ? off : 0;
                const float x = chunk[2 * a];
                const float y = chunk[2 * a + 1];
                if (m) { gx[bb][w] = x; gy[bb][w] = y; }
            }
        }
    }

    // ---- norm2 block reduction (full row per block; half 0 writes) ----
#pragma unroll
    for (int off = 32; off > 0; off >>= 1) nacc += __shfl_down(nacc, off, 64);
    if ((t & 63) == 0) sm[t >> 6] = nacc;
    __syncthreads();
    if (t == 0 && half == 0) {
        float s = 0.0f;
#pragma unroll
        for (int i = 0; i < 8; ++i) s += sm[i];
        norm2[k] = s;
    }

    // ---- score math (divergence-free), exact numpy pairwise-8 order ----
#pragma unroll
    for (int bb = 0; bb < 2; ++bb) {
        const int b = (bb == 0) ? b0 : b1;
        float phi[WDIM];
#pragma unroll
        for (int w = 0; w < WDIM; ++w) {
            const float2 cs = cst[w * BD + b];
            const float x = gx[bb][w], y = gy[bb][w];
            const float mag = hypotf(x, y);
            const float re  = __fadd_rn(__fmul_rn(x, cs.x), __fmul_rn(y, cs.y));
            const float im  = __fsub_rn(__fmul_rn(y, cs.x), __fmul_rn(x, cs.y));
            phi[w] = __fadd_rn(mag, fabsf(atan2f(im, re)));
        }
        const float r0 = __fadd_rn(phi[0], phi[8]);
        const float r1 = __fadd_rn(phi[1], phi[9]);
        const float r2 = __fadd_rn(phi[2], phi[10]);
        const float r3 = __fadd_rn(phi[3], phi[11]);
        const float r4 = __fadd_rn(phi[4], phi[12]);
        const float r5 = __fadd_rn(phi[5], phi[13]);
        const float r6 = __fadd_rn(phi[6], phi[14]);
        const float r7 = __fadd_rn(phi[7], phi[15]);
        float score = __fadd_rn(__fadd_rn(__fadd_rn(r0, r1), __fadd_rn(r2, r3)),
                                __fadd_rn(__fadd_rn(r4, r5), __fadd_rn(r6, r7)));
        score = __fadd_rn(score, phi[16]);
        score = __fadd_rn(score, phi[17]);
        score = __fadd_rn(score, phi[18]);
        score = __fadd_rn(score, phi[19]);

        // fused argmax: score>0 -> f32 bits order-preserving; ties ->
        // larger (KD-1-k) wins = smaller k (stable argsort semantics)
        const unsigned long long packed =
            ((unsigned long long)__float_as_uint(score) << 32) |
            (unsigned long long)(unsigned)(KD - 1 - k);
        atomicMax(&amax[b], packed);
    }
}

// ---------------------------------------------------------------------------
// decode amax -> mu (out + mu_int)
// ---------------------------------------------------------------------------
__global__ __launch_bounds__(256) void decode_kernel(
    const unsigned long long* __restrict__ amax,
    float* __restrict__ out,
    int*   __restrict__ mu_int)
{
    const int b = blockIdx.x * 256 + threadIdx.x;
    if (b >= BD) return;
    const int mu = KD - 1 - (int)(amax[b] & 0xFFFFFFFFull);
    mu_int[b] = mu;
    out[b] = (float)mu;
}

// ---------------------------------------------------------------------------
// per-batch energy contribution
// ---------------------------------------------------------------------------
__global__ __launch_bounds__(64) void e_kernel(
    const float* __restrict__ W,
    const float* __restrict__ Ps,
    const float* __restrict__ pos,
    const int*   __restrict__ ids,
    const int*   __restrict__ mu_int,
    const float* __restrict__ norm2,
    float* __restrict__ contrib)
{
    const int b = blockIdx.x;
    const int t = threadIdx.x;
    const int mu = mu_int[b];
    const float* Wm = W + (size_t)mu * (VD * 2);

    float loc_abs = 0.0f, loc_phi = 0.0f;
    if (t < WDIM) {
        const int id = ids[b * WDIM + t];
        const float P = Ps[b * WDIM + t];
        const float pf = __fmul_rn(pos[b * WDIM + t], PI_F);
        const float c = cosf(pf), s = sinf(pf);
        const float2 g = *reinterpret_cast<const float2*>(Wm + 2 * (size_t)id);
        float re = P * (g.x * c + g.y * s);
        float im = P * (g.y * c - g.x * s);
        if (re < THRV && re > -THRV) re = THRV;
        if (im < THRV && im > -THRV) im = THRV;
        loc_abs = sqrtf(re * re + im * im);
        loc_phi = fabsf(atan2f(im, re)) * P;
    }
#pragma unroll
    for (int off = 32; off > 0; off >>= 1) {
        loc_abs += __shfl_down(loc_abs, off, 64);
        loc_phi += __shfl_down(loc_phi, off, 64);
    }
    if (t == 0) {
        const float den = sqrtf(norm2[mu]);
        contrib[b] = loc_abs / den + loc_phi;
    }
}

// ---------------------------------------------------------------------------
// final reduction (f64 accum), E -> out[2048]
// ---------------------------------------------------------------------------
__global__ __launch_bounds__(256) void finalize_kernel(
    const float* __restrict__ contrib,
    float* __restrict__ out)
{
    __shared__ double sm[4];
    double acc = 0.0;
    for (int i = threadIdx.x; i < BD; i += 256) acc += (double)contrib[i];
#pragma unroll
    for (int off = 32; off > 0; off >>= 1) acc += __shfl_down(acc, off, 64);
    if ((threadIdx.x & 63) == 0) sm[threadIdx.x >> 6] = acc;
    __syncthreads();
    if (threadIdx.x == 0) {
        double s = sm[0] + sm[1] + sm[2] + sm[3];
        out[BD] = (float)(-s);
    }
}

// ---------------------------------------------------------------------------
// Fallback (round-5 passing path) if ws_size is too small
// ---------------------------------------------------------------------------
__global__ __launch_bounds__(1024) void scores_kernel_fb(
    const float* __restrict__ W,
    const float* __restrict__ pos,
    const int*   __restrict__ ids,
    float* __restrict__ out,
    int* __restrict__ mu_int)
{
    __shared__ int   s_id[WDIM];
    __shared__ float s_c[WDIM];
    __shared__ float s_s[WDIM];
    __shared__ float r_val[16];
    __shared__ int   r_idx[16];

    const int b = blockIdx.x;
    const int t = threadIdx.x;

    if (t < WDIM) {
        s_id[t] = ids[b * WDIM + t];
        const float pf = __fmul_rn(pos[b * WDIM + t], PI_F);
        s_c[t] = cosf(pf);
        s_s[t] = sinf(pf);
    }
    __syncthreads();

    const float* Wk = W + (size_t)t * (VD * 2);
    float phi[WDIM];
#pragma unroll
    for (int w = 0; w < WDIM; ++w) {
        const float2 g = *reinterpret_cast<const float2*>(Wk + 2 * (size_t)s_id[w]);
        const float c = s_c[w], s = s_s[w];
        const float mag = hypotf(g.x, g.y);
        const float re = __fadd_rn(__fmul_rn(g.x, c), __fmul_rn(g.y, s));
        const float im = __fsub_rn(__fmul_rn(g.y, c), __fmul_rn(g.x, s));
        phi[w] = __fadd_rn(mag, fabsf(atan2f(im, re)));
    }
    const float r0 = __fadd_rn(phi[0], phi[8]);
    const float r1 = __fadd_rn(phi[1], phi[9]);
    const float r2 = __fadd_rn(phi[2], phi[10]);
    const float r3 = __fadd_rn(phi[3], phi[11]);
    const float r4 = __fadd_rn(phi[4], phi[12]);
    const float r5 = __fadd_rn(phi[5], phi[13]);
    const float r6 = __fadd_rn(phi[6], phi[14]);
    const float r7 = __fadd_rn(phi[7], phi[15]);
    float score = __fadd_rn(__fadd_rn(__fadd_rn(r0, r1), __fadd_rn(r2, r3)),
                            __fadd_rn(__fadd_rn(r4, r5), __fadd_rn(r6, r7)));
    score = __fadd_rn(score, phi[16]);
    score = __fadd_rn(score, phi[17]);
    score = __fadd_rn(score, phi[18]);
    score = __fadd_rn(score, phi[19]);

    float v = score; int vi = t;
#pragma unroll
    for (int off = 32; off > 0; off >>= 1) {
        float ov = __shfl_down(v, off, 64);
        int   oi = __shfl_down(vi, off, 64);
        if (ov > v || (ov == v && oi < vi)) { v = ov; vi = oi; }
    }
    if ((t & 63) == 0) { r_val[t >> 6] = v; r_idx[t >> 6] = vi; }
    __syncthreads();
    if (t == 0) {
        float bv = r_val[0]; int bi = r_idx[0];
#pragma unroll
        for (int i = 1; i < 16; ++i) {
            if (r_val[i] > bv || (r_val[i] == bv && r_idx[i] < bi)) {
                bv = r_val[i]; bi = r_idx[i];
            }
        }
        mu_int[b] = bi;
        out[b] = (float)bi;
    }
}

__global__ __launch_bounds__(512) void norm_kernel_fb(
    const float* __restrict__ W,
    float* __restrict__ norm2)
{
    const int k = blockIdx.x;
    const float4* row = reinterpret_cast<const float4*>(W + (size_t)k * (VD * 2));
    const int n4 = (VD * 2) / 4;
    float acc = 0.0f;
    for (int i = threadIdx.x; i < n4; i += 512) {
        float4 v = row[i];
        acc += v.x * v.x + v.y * v.y + v.z * v.z + v.w * v.w;
    }
    __shared__ float sm[8];
#pragma unroll
    for (int off = 32; off > 0; off >>= 1) acc += __shfl_down(acc, off, 64);
    if ((threadIdx.x & 63) == 0) sm[threadIdx.x >> 6] = acc;
    __syncthreads();
    if (threadIdx.x == 0) {
        float s = 0.0f;
#pragma unroll
        for (int i = 0; i < 8; ++i) s += sm[i];
        norm2[k] = s;
    }
}

extern "C" void kernel_launch(void* const* d_in, const int* in_sizes, int n_in,
                              void* d_out, int out_size, void* d_ws, size_t ws_size,
                              hipStream_t stream) {
    const float* W   = (const float*)d_in[0];  // (K, V, 2) fp32
    const float* Ps  = (const float*)d_in[1];  // (B, WD) fp32
    const float* pos = (const float*)d_in[2];  // (B, WD) fp32
    const int*   ids = (const int*)d_in[3];    // (B, WD) int32

    float* out = (float*)d_out;                // float32[2049]

    // ws layout (8B alignment first)
    char* p = (char*)d_ws;
    unsigned long long* amax = (unsigned long long*)p;  p += (size_t)BD * 8;
    float2*       cst     = (float2*)p;                 p += (size_t)WDIM * BD * 8;
    unsigned int* idp     = (unsigned int*)p;           p += (size_t)(WDIM / 2) * BD * 4;
    float*        norm2   = (float*)p;                  p += KD * 4;
    float*        contrib = (float*)p;                  p += BD * 4;
    int*          mu_int  = (int*)p;                    p += BD * 4;
    const size_t need = (size_t)(p - (char*)d_ws);

    if (ws_size >= need) {
        prep_kernel<<<(BD + 255) / 256, 256, 0, stream>>>(pos, ids, cst, idp);
        zero64_kernel<<<(BD + 255) / 256, 256, 0, stream>>>(amax);
        half_kernel<<<KD * 2, 512, 0, stream>>>(W, idp, cst, norm2, amax);
        decode_kernel<<<(BD + 255) / 256, 256, 0, stream>>>(amax, out, mu_int);
    } else {
        scores_kernel_fb<<<BD, 1024, 0, stream>>>(W, pos, ids, out, mu_int);
        norm_kernel_fb<<<KD, 512, 0, stream>>>(W, norm2);
    }
    e_kernel<<<BD, 64, 0, stream>>>(W, Ps, pos, ids, mu_int, norm2, contrib);
    finalize_kernel<<<1, 256, 0, stream>>>(contrib, out);
}

// Round 20
// 179.218 us; speedup vs baseline: 1.2096x; 1.2096x over previous
//
#include <hip/hip_runtime.h>
#include <hip/hip_bf16.h>
#include <math.h>

#define KD 1024
#define VD 50000
#define BD 2048
#define WDIM 20
#define THRV 1e-10f
#define PI_F 3.14159274101257324f  /* 0x40490FDB — f32(pi) */

#define NCHUNK 4
#define CHUNK 12500              /* complex elements per chunk; 4*12500 = VD */

// d_out is FLOAT32[2049]: [0..2048) = mu (as float), [2048] = E.
//
// Round-20: r18 row_kernel byte-identical (best measured: 182.7us total,
// VGPR 64 + ~64 AGPR = 128/thread -> 1 block/CU, structural serial floor
// ~160us: stream 65 HBM + match/score VALU ~60 + barriers). r19 proved
// co-resident-block overlap doesn't materialize (lockstep barriers) and
// costs 2x stream. This round only fuses aux: amax-zero into prep, decode
// into e_kernel (saves 2 launches). mu/E math untouched.

// ---------------------------------------------------------------------------
// prep: cst[w][b]=(cos,sin)(pi*pos[b][w]); idp packed u16 id pairs;
// also zeroes amax[b] (ws poisoned 0xAA each timing run -> must re-init).
// ---------------------------------------------------------------------------
__global__ __launch_bounds__(256) void prep_kernel(
    const float* __restrict__ pos,
    const int*   __restrict__ ids,
    float2* __restrict__ cst,
    unsigned int* __restrict__ idp,
    unsigned long long* __restrict__ amax)
{
    const int b = blockIdx.x * 256 + threadIdx.x;
    if (b >= BD) return;
    amax[b] = 0ull;
    int idv[WDIM];
#pragma unroll
    for (int w = 0; w < WDIM; ++w) {
        idv[w] = ids[b * WDIM + w];
        const float pf = __fmul_rn(pos[b * WDIM + w], PI_F);
        cst[w * BD + b] = make_float2(cosf(pf), sinf(pf));
    }
#pragma unroll
    for (int j = 0; j < WDIM / 2; ++j)
        idp[j * BD + b] = (unsigned int)idv[2 * j] |
                          ((unsigned int)idv[2 * j + 1] << 16);
}

// ---------------------------------------------------------------------------
// row_kernel (r18 body, byte-identical): one block per W row k. Stream the
// row through LDS in 4 chunks (coalesced; W read once; norm2 fused); match
// phase copies float2 -> registers; hypot/atan2 once at the end,
// divergence-free, exact numpy pairwise-8 order; packed-u64 atomicMax.
// ---------------------------------------------------------------------------
__global__ __launch_bounds__(1024, 4) void row_kernel(
    const float* __restrict__ W,
    const unsigned int* __restrict__ idp,
    const float2* __restrict__ cst,
    float* __restrict__ norm2,
    unsigned long long* __restrict__ amax)
{
    __shared__ __align__(16) float chunk[CHUNK * 2];   // 100 KB
    __shared__ float sm[16];

    const int k = blockIdx.x;
    const int t = threadIdx.x;
    const float* Wk = W + (size_t)k * (VD * 2);

    // per-thread ids for b = t and b = t + 1024 (packed u16 pairs)
    unsigned int idreg[2][WDIM / 2];
#pragma unroll
    for (int j = 0; j < WDIM / 2; ++j) {
        idreg[0][j] = idp[j * BD + t];
        idreg[1][j] = idp[j * BD + t + 1024];
    }

    float gx[2][WDIM], gy[2][WDIM];
#pragma unroll
    for (int w = 0; w < WDIM; ++w) {
        gx[0][w] = 0.f; gy[0][w] = 0.f; gx[1][w] = 0.f; gy[1][w] = 0.f;
    }

    float nacc = 0.0f;

    for (int c = 0; c < NCHUNK; ++c) {
        __syncthreads();   // protect chunk from previous iteration's readers
        // ---- coalesced chunk stream + norm2 partial ----
        const float4* src = reinterpret_cast<const float4*>(Wk + c * (CHUNK * 2));
        float4* dst = reinterpret_cast<float4*>(chunk);
        for (int i = t; i < (CHUNK * 2) / 4; i += 1024) {
            const float4 v = src[i];
            dst[i] = v;
            nacc += v.x * v.x + v.y * v.y + v.z * v.z + v.w * v.w;
        }
        __syncthreads();

        // ---- match phase: copy g for ids inside this chunk ----
        const int lo = c * CHUNK;
#pragma unroll
        for (int bb = 0; bb < 2; ++bb) {
#pragma unroll
            for (int w = 0; w < WDIM; ++w) {
                const int id  = (int)((idreg[bb][w >> 1] >> ((w & 1) * 16)) & 0xFFFFu);
                const int off = id - lo;
                const bool m  = (unsigned)off < (unsigned)CHUNK;
                const int a   = m ? off : 0;
                const float x = chunk[2 * a];
                const float y = chunk[2 * a + 1];
                if (m) { gx[bb][w] = x; gy[bb][w] = y; }
            }
        }
    }

    // ---- norm2 block reduction ----
#pragma unroll
    for (int off = 32; off > 0; off >>= 1) nacc += __shfl_down(nacc, off, 64);
    if ((t & 63) == 0) sm[t >> 6] = nacc;
    __syncthreads();
    if (t == 0) {
        float s = 0.0f;
#pragma unroll
        for (int i = 0; i < 16; ++i) s += sm[i];
        norm2[k] = s;
    }

    // ---- score math (divergence-free), exact numpy pairwise-8 order ----
#pragma unroll
    for (int bb = 0; bb < 2; ++bb) {
        const int b = t + bb * 1024;
        float phi[WDIM];
#pragma unroll
        for (int w = 0; w < WDIM; ++w) {
            const float2 cs = cst[w * BD + b];
            const float x = gx[bb][w], y = gy[bb][w];
            const float mag = hypotf(x, y);
            const float re  = __fadd_rn(__fmul_rn(x, cs.x), __fmul_rn(y, cs.y));
            const float im  = __fsub_rn(__fmul_rn(y, cs.x), __fmul_rn(x, cs.y));
            phi[w] = __fadd_rn(mag, fabsf(atan2f(im, re)));
        }
        const float r0 = __fadd_rn(phi[0], phi[8]);
        const float r1 = __fadd_rn(phi[1], phi[9]);
        const float r2 = __fadd_rn(phi[2], phi[10]);
        const float r3 = __fadd_rn(phi[3], phi[11]);
        const float r4 = __fadd_rn(phi[4], phi[12]);
        const float r5 = __fadd_rn(phi[5], phi[13]);
        const float r6 = __fadd_rn(phi[6], phi[14]);
        const float r7 = __fadd_rn(phi[7], phi[15]);
        float score = __fadd_rn(__fadd_rn(__fadd_rn(r0, r1), __fadd_rn(r2, r3)),
                                __fadd_rn(__fadd_rn(r4, r5), __fadd_rn(r6, r7)));
        score = __fadd_rn(score, phi[16]);
        score = __fadd_rn(score, phi[17]);
        score = __fadd_rn(score, phi[18]);
        score = __fadd_rn(score, phi[19]);

        // fused argmax: score>0 so f32 bits are order-preserving; ties ->
        // larger (KD-1-k) wins = smaller k (stable argsort semantics)
        const unsigned long long packed =
            ((unsigned long long)__float_as_uint(score) << 32) |
            (unsigned long long)(unsigned)(KD - 1 - k);
        atomicMax(&amax[b], packed);
    }
}

// ---------------------------------------------------------------------------
// e_kernel: decodes amax inline (use_amax=1) or reads mu_int (fallback);
// writes out[b] = mu and contrib[b].
// ---------------------------------------------------------------------------
__global__ __launch_bounds__(64) void e_kernel(
    const float* __restrict__ W,
    const float* __restrict__ Ps,
    const float* __restrict__ pos,
    const int*   __restrict__ ids,
    const unsigned long long* __restrict__ amax,
    const int*   __restrict__ mu_int,
    const int    use_amax,
    const float* __restrict__ norm2,
    float* __restrict__ contrib,
    float* __restrict__ out)
{
    const int b = blockIdx.x;
    const int t = threadIdx.x;
    const int mu = use_amax ? (KD - 1 - (int)(amax[b] & 0xFFFFFFFFull))
                            : mu_int[b];
    const float* Wm = W + (size_t)mu * (VD * 2);

    float loc_abs = 0.0f, loc_phi = 0.0f;
    if (t < WDIM) {
        const int id = ids[b * WDIM + t];
        const float P = Ps[b * WDIM + t];
        const float pf = __fmul_rn(pos[b * WDIM + t], PI_F);
        const float c = cosf(pf), s = sinf(pf);
        const float2 g = *reinterpret_cast<const float2*>(Wm + 2 * (size_t)id);
        float re = P * (g.x * c + g.y * s);
        float im = P * (g.y * c - g.x * s);
        if (re < THRV && re > -THRV) re = THRV;
        if (im < THRV && im > -THRV) im = THRV;
        loc_abs = sqrtf(re * re + im * im);
        loc_phi = fabsf(atan2f(im, re)) * P;
    }
#pragma unroll
    for (int off = 32; off > 0; off >>= 1) {
        loc_abs += __shfl_down(loc_abs, off, 64);
        loc_phi += __shfl_down(loc_phi, off, 64);
    }
    if (t == 0) {
        if (use_amax) out[b] = (float)mu;
        const float den = sqrtf(norm2[mu]);
        contrib[b] = loc_abs / den + loc_phi;
    }
}

// ---------------------------------------------------------------------------
// final reduction (f64 accum), E -> out[2048]
// ---------------------------------------------------------------------------
__global__ __launch_bounds__(256) void finalize_kernel(
    const float* __restrict__ contrib,
    float* __restrict__ out)
{
    __shared__ double sm[4];
    double acc = 0.0;
    for (int i = threadIdx.x; i < BD; i += 256) acc += (double)contrib[i];
#pragma unroll
    for (int off = 32; off > 0; off >>= 1) acc += __shfl_down(acc, off, 64);
    if ((threadIdx.x & 63) == 0) sm[threadIdx.x >> 6] = acc;
    __syncthreads();
    if (threadIdx.x == 0) {
        double s = sm[0] + sm[1] + sm[2] + sm[3];
        out[BD] = (float)(-s);
    }
}

// ---------------------------------------------------------------------------
// Fallback (round-5 passing path) if ws_size is too small
// ---------------------------------------------------------------------------
__global__ __launch_bounds__(1024) void scores_kernel_fb(
    const float* __restrict__ W,
    const float* __restrict__ pos,
    const int*   __restrict__ ids,
    float* __restrict__ out,
    int* __restrict__ mu_int)
{
    __shared__ int   s_id[WDIM];
    __shared__ float s_c[WDIM];
    __shared__ float s_s[WDIM];
    __shared__ float r_val[16];
    __shared__ int   r_idx[16];

    const int b = blockIdx.x;
    const int t = threadIdx.x;

    if (t < WDIM) {
        s_id[t] = ids[b * WDIM + t];
        const float pf = __fmul_rn(pos[b * WDIM + t], PI_F);
        s_c[t] = cosf(pf);
        s_s[t] = sinf(pf);
    }
    __syncthreads();

    const float* Wk = W + (size_t)t * (VD * 2);
    float phi[WDIM];
#pragma unroll
    for (int w = 0; w < WDIM; ++w) {
        const float2 g = *reinterpret_cast<const float2*>(Wk + 2 * (size_t)s_id[w]);
        const float c = s_c[w], s = s_s[w];
        const float mag = hypotf(g.x, g.y);
        const float re = __fadd_rn(__fmul_rn(g.x, c), __fmul_rn(g.y, s));
        const float im = __fsub_rn(__fmul_rn(g.y, c), __fmul_rn(g.x, s));
        phi[w] = __fadd_rn(mag, fabsf(atan2f(im, re)));
    }
    const float r0 = __fadd_rn(phi[0], phi[8]);
    const float r1 = __fadd_rn(phi[1], phi[9]);
    const float r2 = __fadd_rn(phi[2], phi[10]);
    const float r3 = __fadd_rn(phi[3], phi[11]);
    const float r4 = __fadd_rn(phi[4], phi[12]);
    const float r5 = __fadd_rn(phi[5], phi[13]);
    const float r6 = __fadd_rn(phi[6], phi[14]);
    const float r7 = __fadd_rn(phi[7], phi[15]);
    float score = __fadd_rn(__fadd_rn(__fadd_rn(r0, r1), __fadd_rn(r2, r3)),
                            __fadd_rn(__fadd_rn(r4, r5), __fadd_rn(r6, r7)));
    score = __fadd_rn(score, phi[16]);
    score = __fadd_rn(score, phi[17]);
    score = __fadd_rn(score, phi[18]);
    score = __fadd_rn(score, phi[19]);

    float v = score; int vi = t;
#pragma unroll
    for (int off = 32; off > 0; off >>= 1) {
        float ov = __shfl_down(v, off, 64);
        int   oi = __shfl_down(vi, off, 64);
        if (ov > v || (ov == v && oi < vi)) { v = ov; vi = oi; }
    }
    if ((t & 63) == 0) { r_val[t >> 6] = v; r_idx[t >> 6] = vi; }
    __syncthreads();
    if (t == 0) {
        float bv = r_val[0]; int bi = r_idx[0];
#pragma unroll
        for (int i = 1; i < 16; ++i) {
            if (r_val[i] > bv || (r_val[i] == bv && r_idx[i] < bi)) {
                bv = r_val[i]; bi = r_idx[i];
            }
        }
        mu_int[b] = bi;
        out[b] = (float)bi;
    }
}

__global__ __launch_bounds__(512) void norm_kernel_fb(
    const float* __restrict__ W,
    float* __restrict__ norm2)
{
    const int k = blockIdx.x;
    const float4* row = reinterpret_cast<const float4*>(W + (size_t)k * (VD * 2));
    const int n4 = (VD * 2) / 4;
    float acc = 0.0f;
    for (int i = threadIdx.x; i < n4; i += 512) {
        float4 v = row[i];
        acc += v.x * v.x + v.y * v.y + v.z * v.z + v.w * v.w;
    }
    __shared__ float sm[8];
#pragma unroll
    for (int off = 32; off > 0; off >>= 1) acc += __shfl_down(acc, off, 64);
    if ((threadIdx.x & 63) == 0) sm[threadIdx.x >> 6] = acc;
    __syncthreads();
    if (threadIdx.x == 0) {
        float s = 0.0f;
#pragma unroll
        for (int i = 0; i < 8; ++i) s += sm[i];
        norm2[k] = s;
    }
}

extern "C" void kernel_launch(void* const* d_in, const int* in_sizes, int n_in,
                              void* d_out, int out_size, void* d_ws, size_t ws_size,
                              hipStream_t stream) {
    const float* W   = (const float*)d_in[0];  // (K, V, 2) fp32
    const float* Ps  = (const float*)d_in[1];  // (B, WD) fp32
    const float* pos = (const float*)d_in[2];  // (B, WD) fp32
    const int*   ids = (const int*)d_in[3];    // (B, WD) int32

    float* out = (float*)d_out;                // float32[2049]

    // ws layout (8B alignment first)
    char* p = (char*)d_ws;
    unsigned long long* amax = (unsigned long long*)p;  p += (size_t)BD * 8;
    float2*       cst     = (float2*)p;                 p += (size_t)WDIM * BD * 8;
    unsigned int* idp     = (unsigned int*)p;           p += (size_t)(WDIM / 2) * BD * 4;
    float*        norm2   = (float*)p;                  p += KD * 4;
    float*        contrib = (float*)p;                  p += BD * 4;
    int*          mu_int  = (int*)p;                    p += BD * 4;
    const size_t need = (size_t)(p - (char*)d_ws);

    if (ws_size >= need) {
        prep_kernel<<<(BD + 255) / 256, 256, 0, stream>>>(pos, ids, cst, idp, amax);
        row_kernel<<<KD, 1024, 0, stream>>>(W, idp, cst, norm2, amax);
        e_kernel<<<BD, 64, 0, stream>>>(W, Ps, pos, ids, amax, mu_int, 1,
                                        norm2, contrib, out);
    } else {
        scores_kernel_fb<<<BD, 1024, 0, stream>>>(W, pos, ids, out, mu_int);
        norm_kernel_fb<<<KD, 512, 0, stream>>>(W, norm2);
        e_kernel<<<BD, 64, 0, stream>>>(W, Ps, pos, ids, amax, mu_int, 0,
                                        norm2, contrib, out);
    }
    finalize_kernel<<<1, 256, 0, stream>>>(contrib, out);
}

// Round 21
// 177.117 us; speedup vs baseline: 1.2239x; 1.0119x over previous
//
#include <hip/hip_runtime.h>
#include <hip/hip_bf16.h>
#include <math.h>

#define KD 1024
#define VD 50000
#define BD 2048
#define WDIM 20
#define THRV 1e-10f
#define PI_F 3.14159274101257324f  /* 0x40490FDB — f32(pi) */

#define CHUNK 20000              /* complex elems per chunk = 160 KB LDS */
#define NCHUNK 3                 /* 20000 + 20000 + 10000 tail */
#define TAILC 10000

// d_out is FLOAT32[2049]: [0..2048) = mu (as float), [2048] = E.
//
// Round-21: r20 (179.2us) with full-LDS chunks: CHUNK 12500->20000 (160KB,
// fits 163840 pool; r17 ran 143KB). NCHUNK 4->3: match slots 160->120/thread
// (-25% match VALU), barriers 8->6. Stream bytes + all _rn score ops
// bit-identical -> mu/E unchanged. Occupancy already 1 block/CU (reg-state
// forced), unchanged. If neutral: structure is at floor -> ROOFLINE next.

// ---------------------------------------------------------------------------
// prep: cst[w][b]=(cos,sin)(pi*pos[b][w]); idp packed u16 id pairs;
// zeroes amax[b] (ws poisoned 0xAA each timing run).
// ---------------------------------------------------------------------------
__global__ __launch_bounds__(256) void prep_kernel(
    const float* __restrict__ pos,
    const int*   __restrict__ ids,
    float2* __restrict__ cst,
    unsigned int* __restrict__ idp,
    unsigned long long* __restrict__ amax)
{
    const int b = blockIdx.x * 256 + threadIdx.x;
    if (b >= BD) return;
    amax[b] = 0ull;
    int idv[WDIM];
#pragma unroll
    for (int w = 0; w < WDIM; ++w) {
        idv[w] = ids[b * WDIM + w];
        const float pf = __fmul_rn(pos[b * WDIM + w], PI_F);
        cst[w * BD + b] = make_float2(cosf(pf), sinf(pf));
    }
#pragma unroll
    for (int j = 0; j < WDIM / 2; ++j)
        idp[j * BD + b] = (unsigned int)idv[2 * j] |
                          ((unsigned int)idv[2 * j + 1] << 16);
}

// ---------------------------------------------------------------------------
// row_kernel: one block per W row k. Stream the row through 160KB LDS in 3
// chunks (coalesced; W read once; norm2 fused); match phase copies float2 ->
// registers; hypot/atan2 once at the end, divergence-free, exact numpy
// pairwise-8 order; packed-u64 atomicMax argmax.
// ---------------------------------------------------------------------------
__global__ __launch_bounds__(1024, 4) void row_kernel(
    const float* __restrict__ W,
    const unsigned int* __restrict__ idp,
    const float2* __restrict__ cst,
    float* __restrict__ norm2,
    unsigned long long* __restrict__ amax)
{
    __shared__ __align__(16) float chunk[CHUNK * 2];   // 160 KB
    __shared__ float sm[16];

    const int k = blockIdx.x;
    const int t = threadIdx.x;
    const float* Wk = W + (size_t)k * (VD * 2);

    // per-thread ids for b = t and b = t + 1024 (packed u16 pairs)
    unsigned int idreg[2][WDIM / 2];
#pragma unroll
    for (int j = 0; j < WDIM / 2; ++j) {
        idreg[0][j] = idp[j * BD + t];
        idreg[1][j] = idp[j * BD + t + 1024];
    }

    float gx[2][WDIM], gy[2][WDIM];
#pragma unroll
    for (int w = 0; w < WDIM; ++w) {
        gx[0][w] = 0.f; gy[0][w] = 0.f; gx[1][w] = 0.f; gy[1][w] = 0.f;
    }

    float nacc = 0.0f;

    for (int c = 0; c < NCHUNK; ++c) {
        const bool istail = (c == NCHUNK - 1);
        const int nf4 = (istail ? TAILC * 2 : CHUNK * 2) / 4;

        __syncthreads();   // protect chunk from previous iteration's readers
        // ---- coalesced chunk stream + norm2 partial ----
        const float4* src = reinterpret_cast<const float4*>(Wk + (size_t)c * (CHUNK * 2));
        float4* dst = reinterpret_cast<float4*>(chunk);
        for (int i = t; i < nf4; i += 1024) {
            const float4 v = src[i];
            dst[i] = v;
            nacc += v.x * v.x + v.y * v.y + v.z * v.z + v.w * v.w;
        }
        __syncthreads();

        // ---- match phase: copy g for ids inside this chunk ----
        const int lo = c * CHUNK;
        const unsigned lim = istail ? TAILC : CHUNK;
#pragma unroll
        for (int bb = 0; bb < 2; ++bb) {
#pragma unroll
            for (int w = 0; w < WDIM; ++w) {
                const int id  = (int)((idreg[bb][w >> 1] >> ((w & 1) * 16)) & 0xFFFFu);
                const int off = id - lo;
                const bool m  = (unsigned)off < lim;
                const int a   = m ? off : 0;
                const float x = chunk[2 * a];
                const float y = chunk[2 * a + 1];
                if (m) { gx[bb][w] = x; gy[bb][w] = y; }
            }
        }
    }

    // ---- norm2 block reduction ----
#pragma unroll
    for (int off = 32; off > 0; off >>= 1) nacc += __shfl_down(nacc, off, 64);
    if ((t & 63) == 0) sm[t >> 6] = nacc;
    __syncthreads();
    if (t == 0) {
        float s = 0.0f;
#pragma unroll
        for (int i = 0; i < 16; ++i) s += sm[i];
        norm2[k] = s;
    }

    // ---- score math (divergence-free), exact numpy pairwise-8 order ----
#pragma unroll
    for (int bb = 0; bb < 2; ++bb) {
        const int b = t + bb * 1024;
        float phi[WDIM];
#pragma unroll
        for (int w = 0; w < WDIM; ++w) {
            const float2 cs = cst[w * BD + b];
            const float x = gx[bb][w], y = gy[bb][w];
            const float mag = hypotf(x, y);
            const float re  = __fadd_rn(__fmul_rn(x, cs.x), __fmul_rn(y, cs.y));
            const float im  = __fsub_rn(__fmul_rn(y, cs.x), __fmul_rn(x, cs.y));
            phi[w] = __fadd_rn(mag, fabsf(atan2f(im, re)));
        }
        const float r0 = __fadd_rn(phi[0], phi[8]);
        const float r1 = __fadd_rn(phi[1], phi[9]);
        const float r2 = __fadd_rn(phi[2], phi[10]);
        const float r3 = __fadd_rn(phi[3], phi[11]);
        const float r4 = __fadd_rn(phi[4], phi[12]);
        const float r5 = __fadd_rn(phi[5], phi[13]);
        const float r6 = __fadd_rn(phi[6], phi[14]);
        const float r7 = __fadd_rn(phi[7], phi[15]);
        float score = __fadd_rn(__fadd_rn(__fadd_rn(r0, r1), __fadd_rn(r2, r3)),
                                __fadd_rn(__fadd_rn(r4, r5), __fadd_rn(r6, r7)));
        score = __fadd_rn(score, phi[16]);
        score = __fadd_rn(score, phi[17]);
        score = __fadd_rn(score, phi[18]);
        score = __fadd_rn(score, phi[19]);

        // fused argmax: score>0 so f32 bits are order-preserving; ties ->
        // larger (KD-1-k) wins = smaller k (stable argsort semantics)
        const unsigned long long packed =
            ((unsigned long long)__float_as_uint(score) << 32) |
            (unsigned long long)(unsigned)(KD - 1 - k);
        atomicMax(&amax[b], packed);
    }
}

// ---------------------------------------------------------------------------
// e_kernel: decodes amax inline (use_amax=1) or reads mu_int (fallback);
// writes out[b] = mu and contrib[b].
// ---------------------------------------------------------------------------
__global__ __launch_bounds__(64) void e_kernel(
    const float* __restrict__ W,
    const float* __restrict__ Ps,
    const float* __restrict__ pos,
    const int*   __restrict__ ids,
    const unsigned long long* __restrict__ amax,
    const int*   __restrict__ mu_int,
    const int    use_amax,
    const float* __restrict__ norm2,
    float* __restrict__ contrib,
    float* __restrict__ out)
{
    const int b = blockIdx.x;
    const int t = threadIdx.x;
    const int mu = use_amax ? (KD - 1 - (int)(amax[b] & 0xFFFFFFFFull))
                            : mu_int[b];
    const float* Wm = W + (size_t)mu * (VD * 2);

    float loc_abs = 0.0f, loc_phi = 0.0f;
    if (t < WDIM) {
        const int id = ids[b * WDIM + t];
        const float P = Ps[b * WDIM + t];
        const float pf = __fmul_rn(pos[b * WDIM + t], PI_F);
        const float c = cosf(pf), s = sinf(pf);
        const float2 g = *reinterpret_cast<const float2*>(Wm + 2 * (size_t)id);
        float re = P * (g.x * c + g.y * s);
        float im = P * (g.y * c - g.x * s);
        if (re < THRV && re > -THRV) re = THRV;
        if (im < THRV && im > -THRV) im = THRV;
        loc_abs = sqrtf(re * re + im * im);
        loc_phi = fabsf(atan2f(im, re)) * P;
    }
#pragma unroll
    for (int off = 32; off > 0; off >>= 1) {
        loc_abs += __shfl_down(loc_abs, off, 64);
        loc_phi += __shfl_down(loc_phi, off, 64);
    }
    if (t == 0) {
        if (use_amax) out[b] = (float)mu;
        const float den = sqrtf(norm2[mu]);
        contrib[b] = loc_abs / den + loc_phi;
    }
}

// ---------------------------------------------------------------------------
// final reduction (f64 accum), E -> out[2048]
// ---------------------------------------------------------------------------
__global__ __launch_bounds__(256) void finalize_kernel(
    const float* __restrict__ contrib,
    float* __restrict__ out)
{
    __shared__ double sm[4];
    double acc = 0.0;
    for (int i = threadIdx.x; i < BD; i += 256) acc += (double)contrib[i];
#pragma unroll
    for (int off = 32; off > 0; off >>= 1) acc += __shfl_down(acc, off, 64);
    if ((threadIdx.x & 63) == 0) sm[threadIdx.x >> 6] = acc;
    __syncthreads();
    if (threadIdx.x == 0) {
        double s = sm[0] + sm[1] + sm[2] + sm[3];
        out[BD] = (float)(-s);
    }
}

// ---------------------------------------------------------------------------
// Fallback (round-5 passing path) if ws_size is too small
// ---------------------------------------------------------------------------
__global__ __launch_bounds__(1024) void scores_kernel_fb(
    const float* __restrict__ W,
    const float* __restrict__ pos,
    const int*   __restrict__ ids,
    float* __restrict__ out,
    int* __restrict__ mu_int)
{
    __shared__ int   s_id[WDIM];
    __shared__ float s_c[WDIM];
    __shared__ float s_s[WDIM];
    __shared__ float r_val[16];
    __shared__ int   r_idx[16];

    const int b = blockIdx.x;
    const int t = threadIdx.x;

    if (t < WDIM) {
        s_id[t] = ids[b * WDIM + t];
        const float pf = __fmul_rn(pos[b * WDIM + t], PI_F);
        s_c[t] = cosf(pf);
        s_s[t] = sinf(pf);
    }
    __syncthreads();

    const float* Wk = W + (size_t)t * (VD * 2);
    float phi[WDIM];
#pragma unroll
    for (int w = 0; w < WDIM; ++w) {
        const float2 g = *reinterpret_cast<const float2*>(Wk + 2 * (size_t)s_id[w]);
        const float c = s_c[w], s = s_s[w];
        const float mag = hypotf(g.x, g.y);
        const float re = __fadd_rn(__fmul_rn(g.x, c), __fmul_rn(g.y, s));
        const float im = __fsub_rn(__fmul_rn(g.y, c), __fmul_rn(g.x, s));
        phi[w] = __fadd_rn(mag, fabsf(atan2f(im, re)));
    }
    const float r0 = __fadd_rn(phi[0], phi[8]);
    const float r1 = __fadd_rn(phi[1], phi[9]);
    const float r2 = __fadd_rn(phi[2], phi[10]);
    const float r3 = __fadd_rn(phi[3], phi[11]);
    const float r4 = __fadd_rn(phi[4], phi[12]);
    const float r5 = __fadd_rn(phi[5], phi[13]);
    const float r6 = __fadd_rn(phi[6], phi[14]);
    const float r7 = __fadd_rn(phi[7], phi[15]);
    float score = __fadd_rn(__fadd_rn(__fadd_rn(r0, r1), __fadd_rn(r2, r3)),
                            __fadd_rn(__fadd_rn(r4, r5), __fadd_rn(r6, r7)));
    score = __fadd_rn(score, phi[16]);
    score = __fadd_rn(score, phi[17]);
    score = __fadd_rn(score, phi[18]);
    score = __fadd_rn(score, phi[19]);

    float v = score; int vi = t;
#pragma unroll
    for (int off = 32; off > 0; off >>= 1) {
        float ov = __shfl_down(v, off, 64);
        int   oi = __shfl_down(vi, off, 64);
        if (ov > v || (ov == v && oi < vi)) { v = ov; vi = oi; }
    }
    if ((t & 63) == 0) { r_val[t >> 6] = v; r_idx[t >> 6] = vi; }
    __syncthreads();
    if (t == 0) {
        float bv = r_val[0]; int bi = r_idx[0];
#pragma unroll
        for (int i = 1; i < 16; ++i) {
            if (r_val[i] > bv || (r_val[i] == bv && r_idx[i] < bi)) {
                bv = r_val[i]; bi = r_idx[i];
            }
        }
        mu_int[b] = bi;
        out[b] = (float)bi;
    }
}

__global__ __launch_bounds__(512) void norm_kernel_fb(
    const float* __restrict__ W,
    float* __restrict__ norm2)
{
    const int k = blockIdx.x;
    const float4* row = reinterpret_cast<const float4*>(W + (size_t)k * (VD * 2));
    const int n4 = (VD * 2) / 4;
    float acc = 0.0f;
    for (int i = threadIdx.x; i < n4; i += 512) {
        float4 v = row[i];
        acc += v.x * v.x + v.y * v.y + v.z * v.z + v.w * v.w;
    }
    __shared__ float sm[8];
#pragma unroll
    for (int off = 32; off > 0; off >>= 1) acc += __shfl_down(acc, off, 64);
    if ((threadIdx.x & 63) == 0) sm[threadIdx.x >> 6] = acc;
    __syncthreads();
    if (threadIdx.x == 0) {
        float s = 0.0f;
#pragma unroll
        for (int i = 0; i < 8; ++i) s += sm[i];
        norm2[k] = s;
    }
}

extern "C" void kernel_launch(void* const* d_in, const int* in_sizes, int n_in,
                              void* d_out, int out_size, void* d_ws, size_t ws_size,
                              hipStream_t stream) {
    const float* W   = (const float*)d_in[0];  // (K, V, 2) fp32
    const float* Ps  = (const float*)d_in[1];  // (B, WD) fp32
    const float* pos = (const float*)d_in[2];  // (B, WD) fp32
    const int*   ids = (const int*)d_in[3];    // (B, WD) int32

    float* out = (float*)d_out;                // float32[2049]

    // ws layout (8B alignment first)
    char* p = (char*)d_ws;
    unsigned long long* amax = (unsigned long long*)p;  p += (size_t)BD * 8;
    float2*       cst     = (float2*)p;                 p += (size_t)WDIM * BD * 8;
    unsigned int* idp     = (unsigned int*)p;           p += (size_t)(WDIM / 2) * BD * 4;
    float*        norm2   = (float*)p;                  p += KD * 4;
    float*        contrib = (float*)p;                  p += BD * 4;
    int*          mu_int  = (int*)p;                    p += BD * 4;
    const size_t need = (size_t)(p - (char*)d_ws);

    if (ws_size >= need) {
        prep_kernel<<<(BD + 255) / 256, 256, 0, stream>>>(pos, ids, cst, idp, amax);
        row_kernel<<<KD, 1024, 0, stream>>>(W, idp, cst, norm2, amax);
        e_kernel<<<BD, 64, 0, stream>>>(W, Ps, pos, ids, amax, mu_int, 1,
                                        norm2, contrib, out);
    } else {
        scores_kernel_fb<<<BD, 1024, 0, stream>>>(W, pos, ids, out, mu_int);
        norm_kernel_fb<<<KD, 512, 0, stream>>>(W, norm2);
        e_kernel<<<BD, 64, 0, stream>>>(W, Ps, pos, ids, amax, mu_int, 0,
                                        norm2, contrib, out);
    }
    finalize_kernel<<<1, 256, 0, stream>>>(contrib, out);
}